// Round 2
// baseline (332.735 us; speedup 1.0000x reference)
//
#include <hip/hip_runtime.h>
#include <hip/hip_bf16.h>
#include <math.h>

// Problem constants (CausalSelfAttention_84928683311105)
#define B_  2
#define T_  2048
#define C_  2048
#define NH_ 16
#define NKV_ 4
#define HD_ 128
#define NREP_ (NH_/NKV_)     // 4

// fused QKV output layout: [B*T, 3072] ; q @ 0, k @ 2048, v @ 2560
#define QKVLD 3072
#define KOFF  2048
#define VOFF  2560

// q scale: (1/sqrt(d))^2 folded = 1/128, times log2(e) so scores are in
// log2 units and softmax exp is a single native v_exp_f32.
#define QSCALE 0.01127105500694502f

typedef __bf16 bf16x8 __attribute__((ext_vector_type(8)));
typedef float  f32x4  __attribute__((ext_vector_type(4)));
typedef float  f32x16 __attribute__((ext_vector_type(16)));

__device__ inline void gload_lds16(const void* g, void* l) {
    __builtin_amdgcn_global_load_lds((const __attribute__((address_space(1))) void*)g,
                                     (__attribute__((address_space(3))) void*)l, 16, 0, 0);
}

// ---------------------------------------------------------------------------
// cast fp32 -> bf16, 8 elems/thread
// ---------------------------------------------------------------------------
__global__ __launch_bounds__(256) void cast_bf16(const float* __restrict__ src,
                                                 __bf16* __restrict__ dst)
{
    size_t i = ((size_t)blockIdx.x * 256 + threadIdx.x) * 8;
    float4 a = *(const float4*)&src[i];
    float4 b = *(const float4*)&src[i + 4];
    union { __bf16 h[8]; uint4 u; } pk;
    pk.h[0] = (__bf16)a.x; pk.h[1] = (__bf16)a.y; pk.h[2] = (__bf16)a.z; pk.h[3] = (__bf16)a.w;
    pk.h[4] = (__bf16)b.x; pk.h[5] = (__bf16)b.y; pk.h[6] = (__bf16)b.z; pk.h[7] = (__bf16)b.w;
    *(uint4*)&dst[i] = pk.u;
}

// ---------------------------------------------------------------------------
// merged transpose-cast of Wq|Wk|Wv into wqkvT [3072, 2048] bf16.
// col-tile ct: 0..63 -> Wq (ncols 2048), 64..79 -> Wk, 80..95 -> Wv.
// ---------------------------------------------------------------------------
__global__ __launch_bounds__(256) void wtrans_qkv(const float* __restrict__ Wq,
                                                  const float* __restrict__ Wk,
                                                  const float* __restrict__ Wv,
                                                  __bf16* __restrict__ dst)
{
    __shared__ float tl[32][33];
    int ct = blockIdx.x;
    int k0 = blockIdx.y * 32;
    const float* src;
    int ncols, c0, dr0;
    if (ct < 64)      { src = Wq; ncols = 2048; c0 = ct * 32;        dr0 = ct * 32; }
    else if (ct < 80) { src = Wk; ncols = 512;  c0 = (ct - 64) * 32; dr0 = KOFF + (ct - 64) * 32; }
    else              { src = Wv; ncols = 512;  c0 = (ct - 80) * 32; dr0 = VOFF + (ct - 80) * 32; }

    int tid = threadIdx.x;
    int r  = tid >> 3;
    int c4 = (tid & 7) * 4;
    float4 v = *(const float4*)&src[(size_t)(k0 + r) * ncols + c0 + c4];
    tl[r][c4] = v.x; tl[r][c4 + 1] = v.y; tl[r][c4 + 2] = v.z; tl[r][c4 + 3] = v.w;
    __syncthreads();
    union { __bf16 h[4]; uint2 u; } pk;
#pragma unroll
    for (int j = 0; j < 4; ++j) pk.h[j] = (__bf16)tl[c4 + j][r];
    *(uint2*)&dst[(size_t)(dr0 + r) * 2048 + k0 + c4] = pk.u;
}

// plain transpose-cast for Wp
__global__ __launch_bounds__(256) void wtrans(const float* __restrict__ src,
                                              __bf16* __restrict__ dst, int ncols)
{
    __shared__ float tl[32][33];
    int n0 = blockIdx.x * 32;
    int k0 = blockIdx.y * 32;
    int tid = threadIdx.x;
    int r  = tid >> 3;
    int c4 = (tid & 7) * 4;
    float4 v = *(const float4*)&src[(size_t)(k0 + r) * ncols + n0 + c4];
    tl[r][c4] = v.x; tl[r][c4 + 1] = v.y; tl[r][c4 + 2] = v.z; tl[r][c4 + 3] = v.w;
    __syncthreads();
    union { __bf16 h[4]; uint2 u; } pk;
#pragma unroll
    for (int j = 0; j < 4; ++j) pk.h[j] = (__bf16)tl[c4 + j][r];
    *(uint2*)&dst[(size_t)(n0 + r) * 2048 + k0 + c4] = pk.u;
}

// ---------------------------------------------------------------------------
// bf16 MFMA GEMM, single-barrier double-buffered: C = A(MxK) @ Bt^T, Bt [N,K].
// 128x128 tile, BK=32, 4 waves, global_load_lds(16B) prefetch into alt buffer.
// ---------------------------------------------------------------------------
template<typename TOUT>
__global__ __launch_bounds__(256) void gemm_bt(const __bf16* __restrict__ A,
                                               const __bf16* __restrict__ Bt,
                                               TOUT* __restrict__ C,
                                               int M, int N, int K, int ldc)
{
    __shared__ __bf16 As[2][128 * 32];   // [m][k]
    __shared__ __bf16 Bs[2][128 * 32];   // [n][k]

    const int tid  = threadIdx.x;
    const int wv   = tid >> 6;
    const int lane = tid & 63;
    const int grp  = lane >> 4;
    const int id16 = lane & 15;
    const int wr   = wv >> 1;
    const int wc   = wv & 1;

    const int row0 = blockIdx.y * 128;
    const int col0 = blockIdx.x * 128;

    const int sm = tid >> 2;
    const int sk = (tid & 3) << 3;

    const __bf16* ga0 = A  + (size_t)(row0 + sm) * K + sk;
    const __bf16* ga1 = A  + (size_t)(row0 + 64 + sm) * K + sk;
    const __bf16* gb0 = Bt + (size_t)(col0 + sm) * K + sk;
    const __bf16* gb1 = Bt + (size_t)(col0 + 64 + sm) * K + sk;

    f32x4 acc[4][4];
    const f32x4 fz = {0.f, 0.f, 0.f, 0.f};
#pragma unroll
    for (int i = 0; i < 4; ++i)
#pragma unroll
        for (int j = 0; j < 4; ++j) acc[i][j] = fz;

    const int nk = K >> 5;

    // prologue: stage tile 0 into buf 0
    {
        __bf16* a0 = &As[0][wv << 9];
        __bf16* b0 = &Bs[0][wv << 9];
        gload_lds16(ga0, a0);
        gload_lds16(ga1, a0 + 2048);
        gload_lds16(gb0, b0);
        gload_lds16(gb1, b0 + 2048);
    }

    for (int kt = 0; kt < nk; ++kt) {
        const int bufc = kt & 1;
        asm volatile("s_waitcnt vmcnt(0)" ::: "memory");
        __syncthreads();

        if (kt + 1 < nk) {
            const int kb = (kt + 1) << 5;
            __bf16* a0 = &As[1 - bufc][wv << 9];
            __bf16* b0 = &Bs[1 - bufc][wv << 9];
            gload_lds16(ga0 + kb, a0);
            gload_lds16(ga1 + kb, a0 + 2048);
            gload_lds16(gb0 + kb, b0);
            gload_lds16(gb1 + kb, b0 + 2048);
        }

        bf16x8 af[4], bfr[4];
#pragma unroll
        for (int i = 0; i < 4; ++i)
            af[i] = *(const bf16x8*)&As[bufc][((wr << 6) + (i << 4) + id16) * 32 + (grp << 3)];
#pragma unroll
        for (int j = 0; j < 4; ++j)
            bfr[j] = *(const bf16x8*)&Bs[bufc][((wc << 6) + (j << 4) + id16) * 32 + (grp << 3)];
#pragma unroll
        for (int i = 0; i < 4; ++i)
#pragma unroll
            for (int j = 0; j < 4; ++j)
                acc[i][j] = __builtin_amdgcn_mfma_f32_16x16x32_bf16(af[i], bfr[j], acc[i][j], 0, 0, 0);
    }

#pragma unroll
    for (int i = 0; i < 4; ++i) {
        int gr = row0 + (wr << 6) + (i << 4) + (grp << 2);
#pragma unroll
        for (int j = 0; j < 4; ++j) {
            int gc = col0 + (wc << 6) + (j << 4) + id16;
#pragma unroll
            for (int r = 0; r < 4; ++r) {
                if constexpr (sizeof(TOUT) == 4)
                    C[(size_t)(gr + r) * ldc + gc] = acc[i][j][r];
                else
                    C[(size_t)(gr + r) * ldc + gc] = (TOUT)acc[i][j][r];
            }
        }
    }
}

// ---------------------------------------------------------------------------
// RoPE + RMSNorm in-place on bf16 head-vectors inside the strided qkv buffer.
// ---------------------------------------------------------------------------
__global__ __launch_bounds__(256) void rope_rms_b(__bf16* __restrict__ base,
                                                  const float* __restrict__ cosb,
                                                  const float* __restrict__ sinb,
                                                  int nheads, float scale)
{
    int wid  = blockIdx.x * 4 + (threadIdx.x >> 6);
    int lane = threadIdx.x & 63;
    int bt = wid / nheads;
    int hd = wid % nheads;
    int t  = bt % T_;

    __bf16* p = base + (size_t)bt * QKVLD + hd * HD_;
    float c = cosb[t * 64 + lane];
    float s = sinb[t * 64 + lane];
    float x1 = (float)p[lane];
    float x2 = (float)p[lane + 64];
    float r1 = x1 * c - x2 * s;
    float r2 = x1 * s + x2 * c;
    float ss = r1 * r1 + r2 * r2;
#pragma unroll
    for (int off = 32; off; off >>= 1) ss += __shfl_xor(ss, off, 64);
    float inv = rsqrtf(ss * (1.f / 128.f) + 1e-6f) * scale;
    p[lane]      = (__bf16)(r1 * inv);
    p[lane + 64] = (__bf16)(r2 * inv);
}

// ---------------------------------------------------------------------------
// Transpose V out of qkv: -> vt [B,NKV,128,T] bf16.
// ---------------------------------------------------------------------------
__global__ __launch_bounds__(256) void vtrans(const __bf16* __restrict__ qkv,
                                              __bf16* __restrict__ vt)
{
    __shared__ __bf16 tl[32][HD_ + 8];
    int bx  = blockIdx.x;
    int st  = bx & 63;
    int bkv = bx >> 6;
    int b = bkv >> 2, kv = bkv & 3;
    int s0 = st << 5;
    int tid = threadIdx.x;
    {
        int s = tid >> 3;
        int d = (tid & 7) << 4;
        const __bf16* src = qkv + (size_t)(b * T_ + s0 + s) * QKVLD + VOFF + kv * HD_ + d;
        *(bf16x8*)&tl[s][d]     = *(const bf16x8*)src;
        *(bf16x8*)&tl[s][d + 8] = *(const bf16x8*)(src + 8);
    }
    __syncthreads();
    {
        int d  = tid >> 1;
        int sh = (tid & 1) << 4;
        __bf16 tmp[16];
#pragma unroll
        for (int j = 0; j < 16; ++j) tmp[j] = tl[sh + j][d];
        __bf16* dst = vt + ((size_t)(b * NKV_ + kv) * HD_ + d) * T_ + s0 + sh;
        *(bf16x8*)dst       = *(bf16x8*)&tmp[0];
        *(bf16x8*)(dst + 8) = *(bf16x8*)&tmp[8];
    }
}

// ---------------------------------------------------------------------------
// Flash attention v4: 32x32x16 MFMA + in-register softmax (swapped QK^T).
//
// Theory: v3 was LDS-bound (34 ds_read_b128/wave/tile at 16 FLOP/B, plus a
// P LDS roundtrip with lgkmcnt(0) drain). 32x32x16 doubles FLOP per LDS
// fragment byte; the swapped product S^T = mfma(K,Q) leaves each lane's
// softmax row in registers (C layout: col=lane&31=q, row=key), so P->bf16
// pack + one shfl_xor(32) half-exchange builds the PV B-operand without
// touching LDS at all.
//
// Block = 4 waves, one 128-row q-tile (wave wv owns rows qt*128+wv*32..+31),
// KVBLK=64, K/V double-buffered LDS, 16B-chunk XOR swizzle (chunk ^= row&15,
// pre-swizzled global source + swizzled read) -> 2-way conflicts (free).
// PV computed as O^T = mfma(V^T, P^T). Fixed-max softmax retained (|S| <=
// log2e by Cauchy-Schwarz on RMS-normalized q,k).
//
// Causal balance: jjslot<8 -> jj=15-jjslot else jjslot-8, so co-resident
// block pairs (bx, bx+256) sum to 34 k-tiles. Grid 512 = exactly 2/CU.
// ---------------------------------------------------------------------------
__global__ __launch_bounds__(256, 2) void attn32(const __bf16* __restrict__ qkv,
                                                 const __bf16* __restrict__ vbT,
                                                 __bf16* __restrict__ y)
{
    __shared__ __bf16 Ks[2][64 * 128];   // [key][d] , chunk16 ^ (row&15)
    __shared__ __bf16 Vs[2][64 * 128];   // row r: d=r keys0..63 | d=r+64 keys0..63

    const int tid  = threadIdx.x;
    const int wv   = tid >> 6;
    const int lane = tid & 63;
    const int l31  = lane & 31;
    const int h32  = lane >> 5;

    const int bx    = blockIdx.x;        // 512 = 16 jjslot * 32 bh
    const int jslot = bx >> 5;
    const int bh    = bx & 31;
    const int b     = bh >> 4;
    const int h     = bh & 15;
    const int kv    = h >> 2;
    const int jj    = (jslot < 8) ? (15 - jslot) : (jslot - 8);

    const int NT  = 2 * jj + 2;          // k-tiles of 64 keys
    const int qw0 = jj * 128 + wv * 32;  // wave's first q row
    const int qme = qw0 + l31;           // this lane's q

    // ---- staging offsets: LDS dest linear, global source pre-swizzled ----
    size_t koff[4], voff[4];
#pragma unroll
    for (int i = 0; i < 4; ++i) {
        int r  = (wv * 4 + i) * 4 + (lane >> 4);   // LDS row 0..63
        int c  = lane & 15;                        // physical 16B chunk
        int cs = c ^ (r & 15);                     // logical chunk at source
        koff[i] = (size_t)r * (QKVLD * 2) + (size_t)cs * 16;          // K[key=r][d=cs*8]
        int d   = r + ((cs >> 3) << 6);                                // V^T row packing
        voff[i] = (size_t)d * (T_ * 2) + (size_t)(cs & 7) * 16;        // V^T[d][t=(cs&7)*8]
    }
    const char* kg = (const char*)(qkv + (size_t)b * T_ * QKVLD + KOFF + kv * HD_);
    const char* vg = (const char*)(vbT + ((size_t)(b * NKV_ + kv) * HD_) * T_);

    // ---- Q fragments (B operand: col=q=l31, k=d -> qf[s][j] = Q[q][s*16+h32*8+j]) ----
    bf16x8 qf[8];
    {
        const __bf16* qp = qkv + (size_t)(b * T_ + qw0 + l31) * QKVLD + h * HD_ + h32 * 8;
#pragma unroll
        for (int s = 0; s < 8; ++s) qf[s] = *(const bf16x8*)(qp + s * 16);
    }

    f32x16 o[4];
#pragma unroll
    for (int dt = 0; dt < 4; ++dt)
#pragma unroll
        for (int r = 0; r < 16; ++r) o[dt][r] = 0.f;
    float l_p = 0.f;

    // prologue: stage tile 0 into buf 0
    {
        __bf16* kl = &Ks[0][(wv * 4) * 512];
        __bf16* vl = &Vs[0][(wv * 4) * 512];
#pragma unroll
        for (int i = 0; i < 4; ++i) gload_lds16(kg + koff[i], kl + i * 512);
#pragma unroll
        for (int i = 0; i < 4; ++i) gload_lds16(vg + voff[i], vl + i * 512);
    }

    for (int tt = 0; tt < NT; ++tt) {
        const int bufc = tt & 1;
        asm volatile("s_waitcnt vmcnt(0)" ::: "memory");
        __syncthreads();

        if (tt + 1 < NT) {
            const char* kp = kg + (size_t)(tt + 1) * (64 * QKVLD * 2);
            const char* vp = vg + (size_t)(tt + 1) * (64 * 2);
            __bf16* kl = &Ks[1 - bufc][(wv * 4) * 512];
            __bf16* vl = &Vs[1 - bufc][(wv * 4) * 512];
#pragma unroll
            for (int i = 0; i < 4; ++i) gload_lds16(kp + koff[i], kl + i * 512);
#pragma unroll
            for (int i = 0; i < 4; ++i) gload_lds16(vp + voff[i], vl + i * 512);
        }

        const int s0 = tt << 6;
        if (s0 > qw0 + 31) continue;     // wave fully masked (no barriers below)

        // ---- QK^T swapped: S^T[key][q], two 32-key C tiles ----
        f32x16 S0, S1;
#pragma unroll
        for (int r = 0; r < 16; ++r) { S0[r] = 0.f; S1[r] = 0.f; }
        const __bf16* Kb = Ks[bufc];
        __builtin_amdgcn_s_setprio(1);
#pragma unroll
        for (int s = 0; s < 8; ++s) {
            int ch = s * 2 + h32;
            bf16x8 kf0 = *(const bf16x8*)&Kb[l31 * 128 + ((ch ^ (l31 & 15)) << 3)];
            bf16x8 kf1 = *(const bf16x8*)&Kb[(32 + l31) * 128 + ((ch ^ (l31 & 15)) << 3)];
            S0 = __builtin_amdgcn_mfma_f32_32x32x16_bf16(kf0, qf[s], S0, 0, 0, 0);
            S1 = __builtin_amdgcn_mfma_f32_32x32x16_bf16(kf1, qf[s], S1, 0, 0, 0);
        }
        __builtin_amdgcn_s_setprio(0);

        // ---- softmax numerators in-register; pack to bf16 pair words ----
        // lane holds keys rowval(r)=(r&3)+8*(r>>2)+4*h32 (+kt*32) for its q col.
        const bool domask = (s0 + 63 > qw0);
        uint w[16];
#pragma unroll
        for (int i = 0; i < 8; ++i) {
            const int r0 = 2 * i;
            float e0 = exp2f(S0[r0]);
            float e1 = exp2f(S0[r0 + 1]);
            if (domask) {
                int k0 = s0 + (r0 & 3) + 8 * (r0 >> 2) + 4 * h32;
                if (k0     > qme) e0 = 0.f;
                if (k0 + 1 > qme) e1 = 0.f;
            }
            l_p += e0 + e1;
            union { __bf16 h2[2]; uint u; } pk;
            pk.h2[0] = (__bf16)e0; pk.h2[1] = (__bf16)e1;
            w[i] = pk.u;
        }
#pragma unroll
        for (int i = 0; i < 8; ++i) {
            const int r0 = 2 * i;
            float e0 = exp2f(S1[r0]);
            float e1 = exp2f(S1[r0 + 1]);
            if (domask) {
                int k0 = s0 + 32 + (r0 & 3) + 8 * (r0 >> 2) + 4 * h32;
                if (k0     > qme) e0 = 0.f;
                if (k0 + 1 > qme) e1 = 0.f;
            }
            l_p += e0 + e1;
            union { __bf16 h2[2]; uint u; } pk;
            pk.h2[0] = (__bf16)e0; pk.h2[1] = (__bf16)e1;
            w[8 + i] = pk.u;
        }

        // ---- half-exchange: lane needs keys 16s+8*h32+0..7 as P^T B-frag ----
        uint sw[16];
#pragma unroll
        for (int i = 0; i < 16; ++i) sw[i] = (uint)__shfl_xor((int)w[i], 32, 64);

        union U8 { uint u[4]; bf16x8 v; };
        bf16x8 pf[4];
#pragma unroll
        for (int ks = 0; ks < 4; ++ks) {
            const int bsel = ((ks >> 1) << 3) + ((ks & 1) << 2);
            U8 t;
            if (h32 == 0) {
                t.u[0] = w[bsel];      t.u[1] = w[bsel + 1];
                t.u[2] = sw[bsel];     t.u[3] = sw[bsel + 1];
            } else {
                t.u[0] = sw[bsel + 2]; t.u[1] = sw[bsel + 3];
                t.u[2] = w[bsel + 2];  t.u[3] = w[bsel + 3];
            }
            pf[ks] = t.v;
        }

        // ---- PV: O^T[d][q] += V^T[d][key] P^T[key][q] ----
        const __bf16* Vb = Vs[bufc];
        __builtin_amdgcn_s_setprio(1);
#pragma unroll
        for (int dt = 0; dt < 4; ++dt) {
            const int vrow = ((dt & 1) << 5) + l31;
            const int cb   = (dt >> 1) << 3;
#pragma unroll
            for (int ks = 0; ks < 4; ++ks) {
                int ch = cb + ks * 2 + h32;
                bf16x8 vf = *(const bf16x8*)&Vb[vrow * 128 + ((ch ^ (vrow & 15)) << 3)];
                o[dt] = __builtin_amdgcn_mfma_f32_32x32x16_bf16(vf, pf[ks], o[dt], 0, 0, 0);
            }
        }
        __builtin_amdgcn_s_setprio(0);
    }

    // ---- epilogue: l = own partial + other half's partial; scale; store ----
    float l  = l_p + __shfl_xor(l_p, 32, 64);
    float inv = 1.f / l;
    __bf16* yp = y + (size_t)(b * T_ + qw0 + l31) * C_ + h * HD_;
#pragma unroll
    for (int dt = 0; dt < 4; ++dt)
#pragma unroll
        for (int g = 0; g < 4; ++g) {
            union { __bf16 h4[4]; uint2 u; } pk;
#pragma unroll
            for (int e = 0; e < 4; ++e) pk.h4[e] = (__bf16)(o[dt][4 * g + e] * inv);
            *(uint2*)&yp[dt * 32 + 8 * g + 4 * h32] = pk.u;
        }
}

// ---------------------------------------------------------------------------
extern "C" void kernel_launch(void* const* d_in, const int* in_sizes, int n_in,
                              void* d_out, int out_size, void* d_ws, size_t ws_size,
                              hipStream_t stream)
{
    const float* x    = (const float*)d_in[0];
    const float* cosb = (const float*)d_in[1];
    const float* sinb = (const float*)d_in[2];
    const float* Wq   = (const float*)d_in[3];
    const float* Wk   = (const float*)d_in[4];
    const float* Wv   = (const float*)d_in[5];
    const float* Wp   = (const float*)d_in[6];
    float* out = (float*)d_out;

    const int M = B_ * T_;   // 4096

    // workspace: xb | qkv | wqkvT | wpT | vt | y   (all bf16)  ~= 84 MB
    char* w = (char*)d_ws;
    __bf16* xb    = (__bf16*)w;  w += (size_t)M * C_ * 2;
    __bf16* qkv   = (__bf16*)w;  w += (size_t)M * QKVLD * 2;
    __bf16* wqkvT = (__bf16*)w;  w += (size_t)QKVLD * C_ * 2;
    __bf16* wpT   = (__bf16*)w;  w += (size_t)C_ * C_ * 2;
    __bf16* vt    = (__bf16*)w;  w += (size_t)M * NKV_ * HD_ * 2;
    __bf16* y     = (__bf16*)w;

    // casts / transposes
    cast_bf16<<<(M * C_) / 2048, 256, 0, stream>>>(x, xb);
    wtrans_qkv<<<dim3(96, C_ / 32), 256, 0, stream>>>(Wq, Wk, Wv, wqkvT);
    wtrans<<<dim3(C_ / 32, C_ / 32), 256, 0, stream>>>(Wp, wpT, C_);

    // fused QKV projection (bf16 MFMA, dbuf)
    gemm_bt<__bf16><<<dim3(QKVLD / 128, M / 128), 256, 0, stream>>>(xb, wqkvT, qkv, M, QKVLD, C_, QKVLD);

    // RoPE + RMSNorm in-place (q gets 1/128 * log2e; k plain)
    rope_rms_b<<<(M * NH_) / 4, 256, 0, stream>>>(qkv, cosb, sinb, NH_, QSCALE);
    rope_rms_b<<<(M * NKV_) / 4, 256, 0, stream>>>(qkv + KOFF, cosb, sinb, NKV_, 1.0f);

    // V transpose to [B,KV,128,T]
    vtrans<<<B_ * NKV_ * (T_ / 32), 256, 0, stream>>>(qkv, vt);

    // flash attention v4: 32x32 MFMA, in-register softmax
    attn32<<<512, 256, 0, stream>>>(qkv, vt, y);

    // output projection (bf16 MFMA, fp32 out, dbuf)
    gemm_bt<float><<<dim3(C_ / 128, M / 128), 256, 0, stream>>>(y, wpT, out, M, C_, C_, C_);
}

// Round 3
// 327.130 us; speedup vs baseline: 1.0171x; 1.0171x over previous
//
#include <hip/hip_runtime.h>
#include <hip/hip_bf16.h>
#include <math.h>

// Problem constants (CausalSelfAttention_84928683311105)
#define B_  2
#define T_  2048
#define C_  2048
#define NH_ 16
#define NKV_ 4
#define HD_ 128
#define NREP_ (NH_/NKV_)     // 4

// fused QKV output layout: [B*T, 3072] ; q @ 0, k @ 2048, v @ 2560
#define QKVLD 3072
#define KOFF  2048
#define VOFF  2560

// q scale: (1/sqrt(d))^2 folded = 1/128, times log2(e) so scores are in
// log2 units and softmax exp is a single native v_exp_f32.
#define QSCALE 0.01127105500694502f

typedef __bf16 bf16x8 __attribute__((ext_vector_type(8)));
typedef float  f32x4  __attribute__((ext_vector_type(4)));
typedef float  f32x16 __attribute__((ext_vector_type(16)));

__device__ inline void gload_lds16(const void* g, void* l) {
    __builtin_amdgcn_global_load_lds((const __attribute__((address_space(1))) void*)g,
                                     (__attribute__((address_space(3))) void*)l, 16, 0, 0);
}

// ---------------------------------------------------------------------------
// cast fp32 -> bf16, 8 elems/thread
// ---------------------------------------------------------------------------
__global__ __launch_bounds__(256) void cast_bf16(const float* __restrict__ src,
                                                 __bf16* __restrict__ dst)
{
    size_t i = ((size_t)blockIdx.x * 256 + threadIdx.x) * 8;
    float4 a = *(const float4*)&src[i];
    float4 b = *(const float4*)&src[i + 4];
    union { __bf16 h[8]; uint4 u; } pk;
    pk.h[0] = (__bf16)a.x; pk.h[1] = (__bf16)a.y; pk.h[2] = (__bf16)a.z; pk.h[3] = (__bf16)a.w;
    pk.h[4] = (__bf16)b.x; pk.h[5] = (__bf16)b.y; pk.h[6] = (__bf16)b.z; pk.h[7] = (__bf16)b.w;
    *(uint4*)&dst[i] = pk.u;
}

// ---------------------------------------------------------------------------
// merged transpose-cast of Wq|Wk|Wv into wqkvT [3072, 2048] bf16.
// col-tile ct: 0..63 -> Wq (ncols 2048), 64..79 -> Wk, 80..95 -> Wv.
// ---------------------------------------------------------------------------
__global__ __launch_bounds__(256) void wtrans_qkv(const float* __restrict__ Wq,
                                                  const float* __restrict__ Wk,
                                                  const float* __restrict__ Wv,
                                                  __bf16* __restrict__ dst)
{
    __shared__ float tl[32][33];
    int ct = blockIdx.x;
    int k0 = blockIdx.y * 32;
    const float* src;
    int ncols, c0, dr0;
    if (ct < 64)      { src = Wq; ncols = 2048; c0 = ct * 32;        dr0 = ct * 32; }
    else if (ct < 80) { src = Wk; ncols = 512;  c0 = (ct - 64) * 32; dr0 = KOFF + (ct - 64) * 32; }
    else              { src = Wv; ncols = 512;  c0 = (ct - 80) * 32; dr0 = VOFF + (ct - 80) * 32; }

    int tid = threadIdx.x;
    int r  = tid >> 3;
    int c4 = (tid & 7) * 4;
    float4 v = *(const float4*)&src[(size_t)(k0 + r) * ncols + c0 + c4];
    tl[r][c4] = v.x; tl[r][c4 + 1] = v.y; tl[r][c4 + 2] = v.z; tl[r][c4 + 3] = v.w;
    __syncthreads();
    union { __bf16 h[4]; uint2 u; } pk;
#pragma unroll
    for (int j = 0; j < 4; ++j) pk.h[j] = (__bf16)tl[c4 + j][r];
    *(uint2*)&dst[(size_t)(dr0 + r) * 2048 + k0 + c4] = pk.u;
}

// plain transpose-cast for Wp
__global__ __launch_bounds__(256) void wtrans(const float* __restrict__ src,
                                              __bf16* __restrict__ dst, int ncols)
{
    __shared__ float tl[32][33];
    int n0 = blockIdx.x * 32;
    int k0 = blockIdx.y * 32;
    int tid = threadIdx.x;
    int r  = tid >> 3;
    int c4 = (tid & 7) * 4;
    float4 v = *(const float4*)&src[(size_t)(k0 + r) * ncols + n0 + c4];
    tl[r][c4] = v.x; tl[r][c4 + 1] = v.y; tl[r][c4 + 2] = v.z; tl[r][c4 + 3] = v.w;
    __syncthreads();
    union { __bf16 h[4]; uint2 u; } pk;
#pragma unroll
    for (int j = 0; j < 4; ++j) pk.h[j] = (__bf16)tl[c4 + j][r];
    *(uint2*)&dst[(size_t)(n0 + r) * 2048 + k0 + c4] = pk.u;
}

// ---------------------------------------------------------------------------
// bf16 MFMA GEMM, single-barrier double-buffered: C = A(MxK) @ Bt^T, Bt [N,K].
// 128x128 tile, BK=32, 4 waves, global_load_lds(16B) prefetch into alt buffer.
// ---------------------------------------------------------------------------
template<typename TOUT>
__global__ __launch_bounds__(256) void gemm_bt(const __bf16* __restrict__ A,
                                               const __bf16* __restrict__ Bt,
                                               TOUT* __restrict__ C,
                                               int M, int N, int K, int ldc)
{
    __shared__ __bf16 As[2][128 * 32];   // [m][k]
    __shared__ __bf16 Bs[2][128 * 32];   // [n][k]

    const int tid  = threadIdx.x;
    const int wv   = tid >> 6;
    const int lane = tid & 63;
    const int grp  = lane >> 4;
    const int id16 = lane & 15;
    const int wr   = wv >> 1;
    const int wc   = wv & 1;

    const int row0 = blockIdx.y * 128;
    const int col0 = blockIdx.x * 128;

    const int sm = tid >> 2;
    const int sk = (tid & 3) << 3;

    const __bf16* ga0 = A  + (size_t)(row0 + sm) * K + sk;
    const __bf16* ga1 = A  + (size_t)(row0 + 64 + sm) * K + sk;
    const __bf16* gb0 = Bt + (size_t)(col0 + sm) * K + sk;
    const __bf16* gb1 = Bt + (size_t)(col0 + 64 + sm) * K + sk;

    f32x4 acc[4][4];
    const f32x4 fz = {0.f, 0.f, 0.f, 0.f};
#pragma unroll
    for (int i = 0; i < 4; ++i)
#pragma unroll
        for (int j = 0; j < 4; ++j) acc[i][j] = fz;

    const int nk = K >> 5;

    // prologue: stage tile 0 into buf 0
    {
        __bf16* a0 = &As[0][wv << 9];
        __bf16* b0 = &Bs[0][wv << 9];
        gload_lds16(ga0, a0);
        gload_lds16(ga1, a0 + 2048);
        gload_lds16(gb0, b0);
        gload_lds16(gb1, b0 + 2048);
    }

    for (int kt = 0; kt < nk; ++kt) {
        const int bufc = kt & 1;
        asm volatile("s_waitcnt vmcnt(0)" ::: "memory");
        __syncthreads();

        if (kt + 1 < nk) {
            const int kb = (kt + 1) << 5;
            __bf16* a0 = &As[1 - bufc][wv << 9];
            __bf16* b0 = &Bs[1 - bufc][wv << 9];
            gload_lds16(ga0 + kb, a0);
            gload_lds16(ga1 + kb, a0 + 2048);
            gload_lds16(gb0 + kb, b0);
            gload_lds16(gb1 + kb, b0 + 2048);
        }

        bf16x8 af[4], bfr[4];
#pragma unroll
        for (int i = 0; i < 4; ++i)
            af[i] = *(const bf16x8*)&As[bufc][((wr << 6) + (i << 4) + id16) * 32 + (grp << 3)];
#pragma unroll
        for (int j = 0; j < 4; ++j)
            bfr[j] = *(const bf16x8*)&Bs[bufc][((wc << 6) + (j << 4) + id16) * 32 + (grp << 3)];
#pragma unroll
        for (int i = 0; i < 4; ++i)
#pragma unroll
            for (int j = 0; j < 4; ++j)
                acc[i][j] = __builtin_amdgcn_mfma_f32_16x16x32_bf16(af[i], bfr[j], acc[i][j], 0, 0, 0);
    }

#pragma unroll
    for (int i = 0; i < 4; ++i) {
        int gr = row0 + (wr << 6) + (i << 4) + (grp << 2);
#pragma unroll
        for (int j = 0; j < 4; ++j) {
            int gc = col0 + (wc << 6) + (j << 4) + id16;
#pragma unroll
            for (int r = 0; r < 4; ++r) {
                if constexpr (sizeof(TOUT) == 4)
                    C[(size_t)(gr + r) * ldc + gc] = acc[i][j][r];
                else
                    C[(size_t)(gr + r) * ldc + gc] = (TOUT)acc[i][j][r];
            }
        }
    }
}

// ---------------------------------------------------------------------------
// RoPE + RMSNorm in-place on bf16 head-vectors inside the strided qkv buffer.
// ---------------------------------------------------------------------------
__global__ __launch_bounds__(256) void rope_rms_b(__bf16* __restrict__ base,
                                                  const float* __restrict__ cosb,
                                                  const float* __restrict__ sinb,
                                                  int nheads, float scale)
{
    int wid  = blockIdx.x * 4 + (threadIdx.x >> 6);
    int lane = threadIdx.x & 63;
    int bt = wid / nheads;
    int hd = wid % nheads;
    int t  = bt % T_;

    __bf16* p = base + (size_t)bt * QKVLD + hd * HD_;
    float c = cosb[t * 64 + lane];
    float s = sinb[t * 64 + lane];
    float x1 = (float)p[lane];
    float x2 = (float)p[lane + 64];
    float r1 = x1 * c - x2 * s;
    float r2 = x1 * s + x2 * c;
    float ss = r1 * r1 + r2 * r2;
#pragma unroll
    for (int off = 32; off; off >>= 1) ss += __shfl_xor(ss, off, 64);
    float inv = rsqrtf(ss * (1.f / 128.f) + 1e-6f) * scale;
    p[lane]      = (__bf16)(r1 * inv);
    p[lane + 64] = (__bf16)(r2 * inv);
}

// ---------------------------------------------------------------------------
// Transpose V out of qkv: -> vt [B,NKV,128,T] bf16.
// ---------------------------------------------------------------------------
__global__ __launch_bounds__(256) void vtrans(const __bf16* __restrict__ qkv,
                                              __bf16* __restrict__ vt)
{
    __shared__ __bf16 tl[32][HD_ + 8];
    int bx  = blockIdx.x;
    int st  = bx & 63;
    int bkv = bx >> 6;
    int b = bkv >> 2, kv = bkv & 3;
    int s0 = st << 5;
    int tid = threadIdx.x;
    {
        int s = tid >> 3;
        int d = (tid & 7) << 4;
        const __bf16* src = qkv + (size_t)(b * T_ + s0 + s) * QKVLD + VOFF + kv * HD_ + d;
        *(bf16x8*)&tl[s][d]     = *(const bf16x8*)src;
        *(bf16x8*)&tl[s][d + 8] = *(const bf16x8*)(src + 8);
    }
    __syncthreads();
    {
        int d  = tid >> 1;
        int sh = (tid & 1) << 4;
        __bf16 tmp[16];
#pragma unroll
        for (int j = 0; j < 16; ++j) tmp[j] = tl[sh + j][d];
        __bf16* dst = vt + ((size_t)(b * NKV_ + kv) * HD_ + d) * T_ + s0 + sh;
        *(bf16x8*)dst       = *(bf16x8*)&tmp[0];
        *(bf16x8*)(dst + 8) = *(bf16x8*)&tmp[8];
    }
}

// ---------------------------------------------------------------------------
// Flash attention v5: v4's 32x32 in-register-softmax tile math + uniform
// block durations (the v4 regression was occupancy collapse: variable NT
// left heavy blocks alone on a CU at 1 wave/SIMD; measured 12% occupancy).
//
// Work split: for pair p (hi = 15-p >= 8, lo = p), hi-tile has NH = 2hi+2
// k-tiles, lo-tile NL = 2lo+2, NH+NL = 34. Role A: hi k-tiles [0,17).
// Role B: hi k-tiles [17,NH) then lo k-tiles [0,NL) -- (NH-17)+NL = 17.
// Every block runs exactly 17 k-tiles -> 512 blocks, 2/CU, co-resident
// full-duration (2 waves/SIMD steady).
//
// Fixed-max softmax makes partials purely additive: A and B each emit
// (o,l) f32 partials for the hi tile; attn_combine sums and normalizes.
// B writes lo-tile output directly (normalized).
// ---------------------------------------------------------------------------
__global__ __launch_bounds__(256, 2) void attn32(const __bf16* __restrict__ qkv,
                                                 const __bf16* __restrict__ vbT,
                                                 __bf16* __restrict__ y,
                                                 float* __restrict__ pOA,
                                                 float* __restrict__ pOB,
                                                 float* __restrict__ pLA,
                                                 float* __restrict__ pLB)
{
    __shared__ __bf16 Ks[2][64 * 128];   // [key][d] , chunk16 ^ (row&15)
    __shared__ __bf16 Vs[2][64 * 128];   // row r: d=r keys0..63 | d=r+64 keys0..63

    const int tid  = threadIdx.x;
    const int wv   = tid >> 6;
    const int lane = tid & 63;
    const int l31  = lane & 31;
    const int h32  = lane >> 5;

    const int bx   = blockIdx.x;         // 512 = 8 p * 2 role * 32 bh
    const int bh   = bx & 31;
    const int role = (bx >> 5) & 1;      // 0 = A (hi prefix), 1 = B (hi rest + lo)
    const int p    = bx >> 6;            // 0..7
    const int b    = bh >> 4;
    const int h    = bh & 15;
    const int kv   = h >> 2;
    const int slot = p * 32 + bh;

    const int hi  = 15 - p;              // 8..15
    const int lo  = p;                   // 0..7
    const int tts = role ? (15 - 2 * p) : 99;   // B's phase switch (1..15)

    // k-tile index for loop step t (phase-aware)
    auto KT = [&](int t) { return role ? (t < tts ? 17 + t : t - tts) : t; };

    int qw0 = hi * 128 + wv * 32;        // wave's first q row (phase 0)
    int qme = qw0 + l31;

    // ---- staging offsets: LDS dest linear, global source pre-swizzled ----
    size_t koff[4], voff[4];
#pragma unroll
    for (int i = 0; i < 4; ++i) {
        int r  = (wv * 4 + i) * 4 + (lane >> 4);   // LDS row 0..63
        int c  = lane & 15;                        // physical 16B chunk
        int cs = c ^ (r & 15);                     // logical chunk at source
        koff[i] = (size_t)r * (QKVLD * 2) + (size_t)cs * 16;          // K[key=r][d=cs*8]
        int d   = r + ((cs >> 3) << 6);                                // V^T row packing
        voff[i] = (size_t)d * (T_ * 2) + (size_t)(cs & 7) * 16;        // V^T[d][t=(cs&7)*8]
    }
    const char* kg = (const char*)(qkv + (size_t)b * T_ * QKVLD + KOFF + kv * HD_);
    const char* vg = (const char*)(vbT + ((size_t)(b * NKV_ + kv) * HD_) * T_);

    // ---- Q fragments: phase-0 (hi) and phase-1 (lo, role B) ----
    bf16x8 qf[8], qf2[8];
    {
        const __bf16* qp = qkv + (size_t)(b * T_ + hi * 128 + wv * 32 + l31) * QKVLD + h * HD_ + h32 * 8;
#pragma unroll
        for (int s = 0; s < 8; ++s) qf[s] = *(const bf16x8*)(qp + s * 16);
        const __bf16* qp2 = qkv + (size_t)(b * T_ + lo * 128 + wv * 32 + l31) * QKVLD + h * HD_ + h32 * 8;
#pragma unroll
        for (int s = 0; s < 8; ++s) qf2[s] = *(const bf16x8*)(qp2 + s * 16);
    }

    f32x16 o[4];
#pragma unroll
    for (int dt = 0; dt < 4; ++dt)
#pragma unroll
        for (int r = 0; r < 16; ++r) o[dt][r] = 0.f;
    float l_p = 0.f;

#define STORE_PARTIAL(PO, PL)                                                   \
    {                                                                           \
        float lsum = l_p + __shfl_xor(l_p, 32, 64);                             \
        int qloc = wv * 32 + l31;                                               \
        float* po = (PO) + ((size_t)slot * 128 + qloc) * 128;                   \
        _Pragma("unroll")                                                       \
        for (int dt = 0; dt < 4; ++dt)                                          \
            _Pragma("unroll")                                                   \
            for (int g = 0; g < 4; ++g) {                                       \
                float4 f = {o[dt][4 * g + 0], o[dt][4 * g + 1],                 \
                            o[dt][4 * g + 2], o[dt][4 * g + 3]};                \
                *(float4*)&po[dt * 32 + 8 * g + 4 * h32] = f;                   \
            }                                                                   \
        if (h32 == 0) (PL)[slot * 128 + qloc] = lsum;                           \
    }

    // prologue: stage first k-tile into buf 0
    {
        int kt0 = KT(0);
        const char* kp = kg + (size_t)kt0 * (64 * QKVLD * 2);
        const char* vp = vg + (size_t)kt0 * (64 * 2);
        __bf16* kl = &Ks[0][(wv * 4) * 512];
        __bf16* vl = &Vs[0][(wv * 4) * 512];
#pragma unroll
        for (int i = 0; i < 4; ++i) gload_lds16(kp + koff[i], kl + i * 512);
#pragma unroll
        for (int i = 0; i < 4; ++i) gload_lds16(vp + voff[i], vl + i * 512);
    }

    for (int tt = 0; tt < 17; ++tt) {
        const int bufc = tt & 1;
        asm volatile("s_waitcnt vmcnt(0)" ::: "memory");
        __syncthreads();

        if (tt + 1 < 17) {
            int kn = KT(tt + 1);
            const char* kp = kg + (size_t)kn * (64 * QKVLD * 2);
            const char* vp = vg + (size_t)kn * (64 * 2);
            __bf16* kl = &Ks[1 - bufc][(wv * 4) * 512];
            __bf16* vl = &Vs[1 - bufc][(wv * 4) * 512];
#pragma unroll
            for (int i = 0; i < 4; ++i) gload_lds16(kp + koff[i], kl + i * 512);
#pragma unroll
            for (int i = 0; i < 4; ++i) gload_lds16(vp + voff[i], vl + i * 512);
        }

        // B's phase switch: flush hi partial, reset state, swap to lo
        if (role && tt == tts) {
            STORE_PARTIAL(pOB, pLB);
#pragma unroll
            for (int dt = 0; dt < 4; ++dt)
#pragma unroll
                for (int r = 0; r < 16; ++r) o[dt][r] = 0.f;
            l_p = 0.f;
#pragma unroll
            for (int s = 0; s < 8; ++s) qf[s] = qf2[s];
            qw0 = lo * 128 + wv * 32;
            qme = qw0 + l31;
        }

        const int s0 = KT(tt) << 6;
        if (s0 > qw0 + 31) continue;     // wave fully masked (no barriers below)

        // ---- QK^T swapped: S^T[key][q], two 32-key C tiles ----
        f32x16 S0, S1;
#pragma unroll
        for (int r = 0; r < 16; ++r) { S0[r] = 0.f; S1[r] = 0.f; }
        const __bf16* Kb = Ks[bufc];
        __builtin_amdgcn_s_setprio(1);
#pragma unroll
        for (int s = 0; s < 8; ++s) {
            int ch = s * 2 + h32;
            bf16x8 kf0 = *(const bf16x8*)&Kb[l31 * 128 + ((ch ^ (l31 & 15)) << 3)];
            bf16x8 kf1 = *(const bf16x8*)&Kb[(32 + l31) * 128 + ((ch ^ (l31 & 15)) << 3)];
            S0 = __builtin_amdgcn_mfma_f32_32x32x16_bf16(kf0, qf[s], S0, 0, 0, 0);
            S1 = __builtin_amdgcn_mfma_f32_32x32x16_bf16(kf1, qf[s], S1, 0, 0, 0);
        }
        __builtin_amdgcn_s_setprio(0);

        // ---- softmax numerators in-register; pack to bf16 pair words ----
        const bool domask = (s0 + 63 > qw0);
        uint w[16];
#pragma unroll
        for (int i = 0; i < 8; ++i) {
            const int r0 = 2 * i;
            float e0 = exp2f(S0[r0]);
            float e1 = exp2f(S0[r0 + 1]);
            if (domask) {
                int k0 = s0 + (r0 & 3) + 8 * (r0 >> 2) + 4 * h32;
                if (k0     > qme) e0 = 0.f;
                if (k0 + 1 > qme) e1 = 0.f;
            }
            l_p += e0 + e1;
            union { __bf16 h2[2]; uint u; } pk;
            pk.h2[0] = (__bf16)e0; pk.h2[1] = (__bf16)e1;
            w[i] = pk.u;
        }
#pragma unroll
        for (int i = 0; i < 8; ++i) {
            const int r0 = 2 * i;
            float e0 = exp2f(S1[r0]);
            float e1 = exp2f(S1[r0 + 1]);
            if (domask) {
                int k0 = s0 + 32 + (r0 & 3) + 8 * (r0 >> 2) + 4 * h32;
                if (k0     > qme) e0 = 0.f;
                if (k0 + 1 > qme) e1 = 0.f;
            }
            l_p += e0 + e1;
            union { __bf16 h2[2]; uint u; } pk;
            pk.h2[0] = (__bf16)e0; pk.h2[1] = (__bf16)e1;
            w[8 + i] = pk.u;
        }

        // ---- half-exchange: lane needs keys 16s+8*h32+0..7 as P^T B-frag ----
        uint sw[16];
#pragma unroll
        for (int i = 0; i < 16; ++i) sw[i] = (uint)__shfl_xor((int)w[i], 32, 64);

        union U8 { uint u[4]; bf16x8 v; };
        bf16x8 pf[4];
#pragma unroll
        for (int ks = 0; ks < 4; ++ks) {
            const int bsel = ((ks >> 1) << 3) + ((ks & 1) << 2);
            U8 t;
            if (h32 == 0) {
                t.u[0] = w[bsel];      t.u[1] = w[bsel + 1];
                t.u[2] = sw[bsel];     t.u[3] = sw[bsel + 1];
            } else {
                t.u[0] = sw[bsel + 2]; t.u[1] = sw[bsel + 3];
                t.u[2] = w[bsel + 2];  t.u[3] = w[bsel + 3];
            }
            pf[ks] = t.v;
        }

        // ---- PV: O^T[d][q] += V^T[d][key] P^T[key][q] ----
        const __bf16* Vb = Vs[bufc];
        __builtin_amdgcn_s_setprio(1);
#pragma unroll
        for (int dt = 0; dt < 4; ++dt) {
            const int vrow = ((dt & 1) << 5) + l31;
            const int cb   = (dt >> 1) << 3;
#pragma unroll
            for (int ks = 0; ks < 4; ++ks) {
                int ch = cb + ks * 2 + h32;
                bf16x8 vf = *(const bf16x8*)&Vb[vrow * 128 + ((ch ^ (vrow & 15)) << 3)];
                o[dt] = __builtin_amdgcn_mfma_f32_32x32x16_bf16(vf, pf[ks], o[dt], 0, 0, 0);
            }
        }
        __builtin_amdgcn_s_setprio(0);
    }

    // ---- final epilogue ----
    if (role == 0) {
        STORE_PARTIAL(pOA, pLA);
    } else {
        // lo tile: normalize and write y directly
        float l  = l_p + __shfl_xor(l_p, 32, 64);
        float inv = 1.f / l;
        __bf16* yp = y + (size_t)(b * T_ + qw0 + l31) * C_ + h * HD_;
#pragma unroll
        for (int dt = 0; dt < 4; ++dt)
#pragma unroll
            for (int g = 0; g < 4; ++g) {
                union { __bf16 h4[4]; uint2 u; } pk;
#pragma unroll
                for (int e = 0; e < 4; ++e) pk.h4[e] = (__bf16)(o[dt][4 * g + e] * inv);
                *(uint2*)&yp[dt * 32 + 8 * g + 4 * h32] = pk.u;
            }
    }
#undef STORE_PARTIAL
}

// ---------------------------------------------------------------------------
// Combine hi-tile partials: y = (oA + oB) / (lA + lB).  256 blocks x 256 thr.
// ---------------------------------------------------------------------------
__global__ __launch_bounds__(256) void attn_combine(const float* __restrict__ pOA,
                                                    const float* __restrict__ pOB,
                                                    const float* __restrict__ pLA,
                                                    const float* __restrict__ pLB,
                                                    __bf16* __restrict__ y)
{
    int slot = blockIdx.x;               // p*32 + bh
    int p  = slot >> 5, bh = slot & 31;
    int b  = bh >> 4,   h  = bh & 15;
    int hi = 15 - p;
    int t  = threadIdx.x;
    int q  = t >> 1;                     // 0..127
    int dh = (t & 1) << 6;               // 0 or 64

    float inv = 1.f / (pLA[slot * 128 + q] + pLB[slot * 128 + q]);
    size_t base = ((size_t)slot * 128 + q) * 128 + dh;
    __bf16* yp = y + (size_t)(b * T_ + hi * 128 + q) * C_ + h * HD_ + dh;
#pragma unroll
    for (int d0 = 0; d0 < 64; d0 += 8) {
        float4 a0 = *(const float4*)&pOA[base + d0];
        float4 a1 = *(const float4*)&pOA[base + d0 + 4];
        float4 b0 = *(const float4*)&pOB[base + d0];
        float4 b1 = *(const float4*)&pOB[base + d0 + 4];
        union { __bf16 h8[8]; uint4 u; } pk;
        pk.h8[0] = (__bf16)((a0.x + b0.x) * inv);
        pk.h8[1] = (__bf16)((a0.y + b0.y) * inv);
        pk.h8[2] = (__bf16)((a0.z + b0.z) * inv);
        pk.h8[3] = (__bf16)((a0.w + b0.w) * inv);
        pk.h8[4] = (__bf16)((a1.x + b1.x) * inv);
        pk.h8[5] = (__bf16)((a1.y + b1.y) * inv);
        pk.h8[6] = (__bf16)((a1.z + b1.z) * inv);
        pk.h8[7] = (__bf16)((a1.w + b1.w) * inv);
        *(uint4*)&yp[d0] = pk.u;
    }
}

// ---------------------------------------------------------------------------
extern "C" void kernel_launch(void* const* d_in, const int* in_sizes, int n_in,
                              void* d_out, int out_size, void* d_ws, size_t ws_size,
                              hipStream_t stream)
{
    const float* x    = (const float*)d_in[0];
    const float* cosb = (const float*)d_in[1];
    const float* sinb = (const float*)d_in[2];
    const float* Wq   = (const float*)d_in[3];
    const float* Wk   = (const float*)d_in[4];
    const float* Wv   = (const float*)d_in[5];
    const float* Wp   = (const float*)d_in[6];
    float* out = (float*)d_out;

    const int M = B_ * T_;   // 4096

    // workspace: xb | qkv | wqkvT | wpT | vt | y | pOB   (~101 MB)
    // pOA aliases xb (dead after gemm1, exactly 16.78 MB); pL* alias wqkvT.
    char* w = (char*)d_ws;
    __bf16* xb    = (__bf16*)w;  w += (size_t)M * C_ * 2;
    __bf16* qkv   = (__bf16*)w;  w += (size_t)M * QKVLD * 2;
    __bf16* wqkvT = (__bf16*)w;  w += (size_t)QKVLD * C_ * 2;
    __bf16* wpT   = (__bf16*)w;  w += (size_t)C_ * C_ * 2;
    __bf16* vt    = (__bf16*)w;  w += (size_t)M * NKV_ * HD_ * 2;
    __bf16* y     = (__bf16*)w;  w += (size_t)M * C_ * 2;
    float*  pOB   = (float*)w;   // 8*32*128*128*4 = 16.78 MB
    float*  pOA   = (float*)xb;
    float*  pLA   = (float*)wqkvT;
    float*  pLB   = pLA + 8 * 32 * 128;

    // casts / transposes
    cast_bf16<<<(M * C_) / 2048, 256, 0, stream>>>(x, xb);
    wtrans_qkv<<<dim3(96, C_ / 32), 256, 0, stream>>>(Wq, Wk, Wv, wqkvT);
    wtrans<<<dim3(C_ / 32, C_ / 32), 256, 0, stream>>>(Wp, wpT, C_);

    // fused QKV projection (bf16 MFMA, dbuf)
    gemm_bt<__bf16><<<dim3(QKVLD / 128, M / 128), 256, 0, stream>>>(xb, wqkvT, qkv, M, QKVLD, C_, QKVLD);

    // RoPE + RMSNorm in-place (q gets 1/128 * log2e; k plain)
    rope_rms_b<<<(M * NH_) / 4, 256, 0, stream>>>(qkv, cosb, sinb, NH_, QSCALE);
    rope_rms_b<<<(M * NKV_) / 4, 256, 0, stream>>>(qkv + KOFF, cosb, sinb, NKV_, 1.0f);

    // V transpose to [B,KV,128,T]
    vtrans<<<B_ * NKV_ * (T_ / 32), 256, 0, stream>>>(qkv, vt);

    // flash attention v5: uniform 17-tile blocks + additive partials
    attn32<<<512, 256, 0, stream>>>(qkv, vt, y, pOA, pOB, pLA, pLB);
    attn_combine<<<256, 256, 0, stream>>>(pOA, pOB, pLA, pLB, y);

    // output projection (bf16 MFMA, fp32 out, dbuf)
    gemm_bt<float><<<dim3(C_ / 128, M / 128), 256, 0, stream>>>(y, wpT, out, M, C_, C_, C_);
}